// Round 1
// 313.648 us; speedup vs baseline: 1.0044x; 1.0044x over previous
//
#include <hip/hip_runtime.h>
#include <math.h>

// Masked sparsemax via Michelot's active-set algorithm (no sort).
// ONE WAVE (64 lanes) per row: the whole row lives in registers (32 elems/lane),
// the S/C reduction is a pure __shfl_xor butterfly -- no LDS, no __syncthreads,
// no cross-wave convergence lockstep. Each wave retires independently.

constexpr int D    = 2048;
constexpr int WPB  = 4;              // independent waves (= rows) per block
constexpr int TPB  = WPB * 64;       // 256 threads
constexpr int EPT  = D / 64;         // 32 elements per lane
constexpr int CHK  = EPT / 4;        // 8 float4 chunks per lane

__global__ __launch_bounds__(TPB) void sparsemax_kernel(
    const float* __restrict__ x,
    const int*   __restrict__ mask,
    float*       __restrict__ out,
    int n_rows)
{
    const int wave = threadIdx.x >> 6;
    const int lane = threadIdx.x & 63;
    const int row  = blockIdx.x * WPB + wave;
    if (row >= n_rows) return;       // no barriers anywhere, early-return is safe

    const size_t rbase = (size_t)row * D;

    // Coalesced loads: per chunk, the wave reads 64 lanes x 16 B = 1 KiB
    // contiguous for x and for mask. Row ends up fully in registers.
    float z[EPT];
    #pragma unroll
    for (int c = 0; c < CHK; ++c) {
        const size_t off = rbase + (size_t)(c * 256 + lane * 4);
        const float4 a = *(const float4*)(x    + off);
        const int4   m = *(const int4*)  (mask + off);
        z[c * 4 + 0] = m.x ? a.x : -INFINITY;
        z[c * 4 + 1] = m.y ? a.y : -INFINITY;
        z[c * 4 + 2] = m.z ? a.z : -INFINITY;
        z[c * 4 + 3] = m.w ? a.w : -INFINITY;
    }

    // Michelot iteration: theta_{k+1} = (sum_{z>theta_k} z - 1) / |{z>theta_k}|.
    // theta is monotonically nondecreasing; active set shrinks monotonically;
    // converged when the count stops changing (then theta is exact).
    float theta = -INFINITY;         // first pass selects all active entries
    float prevC = -1.0f;

    for (int it = 0; it < 128; ++it) {
        float ps = 0.0f, pc = 0.0f;
        #pragma unroll
        for (int k = 0; k < EPT; ++k) {
            if (z[k] > theta) { ps += z[k]; pc += 1.0f; }
        }
        // wave64 butterfly: every lane ends with the full row sum/count
        #pragma unroll
        for (int off = 32; off > 0; off >>= 1) {
            ps += __shfl_xor(ps, off, 64);
            pc += __shfl_xor(pc, off, 64);
        }
        if (pc == 0.0f) { theta = INFINITY; break; }  // no active -> all zeros
        if (pc == prevC) break;                       // set stable -> exact
        theta = (ps - 1.0f) / pc;
        prevC = pc;
    }

    // p = max(z - theta, 0); masked lanes have z = -inf -> exactly 0
    // (also correct for the all-masked row: -inf - inf = -inf -> 0).
    #pragma unroll
    for (int c = 0; c < CHK; ++c) {
        const size_t off = rbase + (size_t)(c * 256 + lane * 4);
        float4 o;
        o.x = fmaxf(z[c * 4 + 0] - theta, 0.0f);
        o.y = fmaxf(z[c * 4 + 1] - theta, 0.0f);
        o.z = fmaxf(z[c * 4 + 2] - theta, 0.0f);
        o.w = fmaxf(z[c * 4 + 3] - theta, 0.0f);
        *(float4*)(out + off) = o;
    }
}

extern "C" void kernel_launch(void* const* d_in, const int* in_sizes, int n_in,
                              void* d_out, int out_size, void* d_ws, size_t ws_size,
                              hipStream_t stream) {
    const float* x    = (const float*)d_in[0];
    const int*   mask = (const int*)  d_in[1];
    float*       out  = (float*)d_out;
    const int n_rows = in_sizes[0] / D;
    const int blocks = (n_rows + WPB - 1) / WPB;
    sparsemax_kernel<<<blocks, TPB, 0, stream>>>(x, mask, out, n_rows);
}

// Round 2
// 310.840 us; speedup vs baseline: 1.0134x; 1.0090x over previous
//
#include <hip/hip_runtime.h>
#include <math.h>

// Masked sparsemax, one wave (64 lanes) per row, row in registers (32 elems/lane).
//
// Michelot active-set iteration recast as Newton on f(theta) = sum(max(z-theta,0)):
//   theta_{k+1} = theta_k + (f(theta_k) - 1) / C(theta_k),   C = |{z > theta}|
// which is algebraically identical to theta' = (S-1)/C but:
//   - f needs NO compares (sub+max+add, branchless; masked z=-inf contributes 0)
//   - C is computed via per-element __ballot + __popcll: the popcount sum over
//     the 32 register slots IS the whole-row count, identical in every lane,
//     on the SCALAR pipe -- no lane reduction, and the convergence branch is
//     wave-uniform.
// Initial theta = rowmax - 1: sparsemax guarantees theta* >= max-1 (since
// p_max <= 1), and {z > max-1} contains the support, so Michelot's invariants
// hold while the initial active set collapses from ~1024 to a handful.

constexpr int D    = 2048;
constexpr int WPB  = 4;              // waves (= rows) per block
constexpr int TPB  = WPB * 64;       // 256 threads
constexpr int EPT  = D / 64;         // 32 elements per lane
constexpr int CHK  = EPT / 4;        // 8 float4 chunks per lane

__global__ __launch_bounds__(TPB) void sparsemax_kernel(
    const float* __restrict__ x,
    const int*   __restrict__ mask,
    float*       __restrict__ out,
    int n_rows)
{
    const int wave = threadIdx.x >> 6;
    const int lane = threadIdx.x & 63;
    const int row  = blockIdx.x * WPB + wave;
    if (row >= n_rows) return;       // wave-uniform; no barriers anywhere

    const size_t rbase = (size_t)row * D;

    // Coalesced: per chunk the wave reads 1 KiB contiguous from x and mask.
    float z[EPT];
    #pragma unroll
    for (int c = 0; c < CHK; ++c) {
        const size_t off = rbase + (size_t)(c * 256 + lane * 4);
        const float4 a = *(const float4*)(x    + off);
        const int4   m = *(const int4*)  (mask + off);
        z[c * 4 + 0] = m.x ? a.x : -INFINITY;
        z[c * 4 + 1] = m.y ? a.y : -INFINITY;
        z[c * 4 + 2] = m.z ? a.z : -INFINITY;
        z[c * 4 + 3] = m.w ? a.w : -INFINITY;
    }

    // Row max: 4 independent partial chains (short dep chain), then butterfly.
    float m0 = z[0], m1 = z[1], m2 = z[2], m3 = z[3];
    #pragma unroll
    for (int k = 4; k < EPT; k += 4) {
        m0 = fmaxf(m0, z[k + 0]);
        m1 = fmaxf(m1, z[k + 1]);
        m2 = fmaxf(m2, z[k + 2]);
        m3 = fmaxf(m3, z[k + 3]);
    }
    float gmax = fmaxf(fmaxf(m0, m1), fmaxf(m2, m3));
    #pragma unroll
    for (int off = 32; off > 0; off >>= 1)
        gmax = fmaxf(gmax, __shfl_xor(gmax, off, 64));

    float theta;
    if (gmax == -INFINITY) {
        theta = INFINITY;            // all-masked row -> all zeros
    } else {
        theta = gmax - 1.0f;         // valid Michelot start: theta* >= max-1
        int prevC = -1;
        for (int it = 0; it < 64; ++it) {
            // f(theta): branchless, 4 independent accumulator chains.
            float f0 = 0.0f, f1 = 0.0f, f2 = 0.0f, f3 = 0.0f;
            #pragma unroll
            for (int k = 0; k < EPT; k += 4) {
                f0 += fmaxf(z[k + 0] - theta, 0.0f);
                f1 += fmaxf(z[k + 1] - theta, 0.0f);
                f2 += fmaxf(z[k + 2] - theta, 0.0f);
                f3 += fmaxf(z[k + 3] - theta, 0.0f);
            }
            float f = (f0 + f1) + (f2 + f3);
            // C(theta): scalar-pipe popcount of per-slot ballots; every lane
            // ends with the full row count (no lane reduction needed).
            int C = 0;
            #pragma unroll
            for (int k = 0; k < EPT; ++k)
                C += (int)__popcll(__ballot(z[k] > theta));
            // only f needs the cross-lane butterfly
            #pragma unroll
            for (int off = 32; off > 0; off >>= 1)
                f += __shfl_xor(f, off, 64);

            if (C == 0) break;       // defensive (cannot happen: z_max > theta*)
            if (C == prevC) break;   // set stable -> theta already exact
            theta += (f - 1.0f) / (float)C;
            prevC = C;
        }
    }

    // p = max(z - theta, 0); masked lanes (z=-inf) give exactly 0, including
    // the all-masked case (-inf - inf = -inf -> 0 after fmax).
    #pragma unroll
    for (int c = 0; c < CHK; ++c) {
        const size_t off = rbase + (size_t)(c * 256 + lane * 4);
        float4 o;
        o.x = fmaxf(z[c * 4 + 0] - theta, 0.0f);
        o.y = fmaxf(z[c * 4 + 1] - theta, 0.0f);
        o.z = fmaxf(z[c * 4 + 2] - theta, 0.0f);
        o.w = fmaxf(z[c * 4 + 3] - theta, 0.0f);
        *(float4*)(out + off) = o;
    }
}

extern "C" void kernel_launch(void* const* d_in, const int* in_sizes, int n_in,
                              void* d_out, int out_size, void* d_ws, size_t ws_size,
                              hipStream_t stream) {
    const float* x    = (const float*)d_in[0];
    const int*   mask = (const int*)  d_in[1];
    float*       out  = (float*)d_out;
    const int n_rows = in_sizes[0] / D;
    const int blocks = (n_rows + WPB - 1) / WPB;
    sparsemax_kernel<<<blocks, TPB, 0, stream>>>(x, mask, out, n_rows);
}